// Round 8
// baseline (240.475 us; speedup 1.0000x reference)
//
#include <hip/hip_runtime.h>
#include <hip/hip_bf16.h>

#define B_TOK 16384
#define TOPK 2
#define NEXP 64
#define HID 512
#define FFN 1024
#define NASSIGN (B_TOK * TOPK)   // 32768
#define CAP (NASSIGN / NEXP)     // 512 assignments per expert (balanced)

typedef unsigned short u16;
typedef __bf16 bf16_t;
typedef bf16_t bf16x8 __attribute__((ext_vector_type(8)));
typedef float f32x4 __attribute__((ext_vector_type(4)));

// native cvt: compiler emits v_cvt_pk_bf16_f32 for pairs (RTNE)
__device__ __forceinline__ unsigned pkbf(float a, float b) {
  union { bf16_t h[2]; unsigned u; } v;
  v.h[0] = (bf16_t)a; v.h[1] = (bf16_t)b;
  return v.u;
}
__device__ __forceinline__ u16 f2bf(float f) {
  union { bf16_t h; u16 u; } v; v.h = (bf16_t)f; return v.u;
}
__device__ __forceinline__ float bf2f(unsigned u16v) {
  union { unsigned u; float f; } v; v.u = u16v << 16; return v.f;
}

#define GLOAD_LDS16(g, l)                                                     \
  __builtin_amdgcn_global_load_lds((const __attribute__((address_space(1))) void*)(g), \
                                   (__attribute__((address_space(3))) void*)(l), 16, 0, 0)

// ---------------------------------------------------------------- routing
__global__ void k_route(const int* __restrict__ ids, int* __restrict__ cnt,
                        int* __restrict__ tok_of, int* __restrict__ slot_pos) {
  int n = blockIdx.x * blockDim.x + threadIdx.x;
  if (n >= NASSIGN) return;
  int e = ids[n];
  int r = atomicAdd(&cnt[e], 1);
  int p = e * CAP + r;
  tok_of[p] = n >> 1;       // token index for sorted slot p
  slot_pos[n] = p;          // inverse map: assignment n -> sorted slot
}

// ------------------------------------------------- gather + fp32->bf16 cast
__global__ void k_gather(const float* __restrict__ hs, const int* __restrict__ tok_of,
                         u16* __restrict__ Xg) {
  int p = blockIdx.x * 4 + (threadIdx.x >> 6);
  int lane = threadIdx.x & 63;
  const float4* src = reinterpret_cast<const float4*>(hs + (size_t)tok_of[p] * HID);
  uint2* dst = reinterpret_cast<uint2*>(Xg + (size_t)p * HID);
#pragma unroll
  for (int i = 0; i < 2; i++) {
    float4 v = src[i * 64 + lane];
    uint2 o;
    o.x = pkbf(v.x, v.y);
    o.y = pkbf(v.z, v.w);
    dst[i * 64 + lane] = o;
  }
}

// ------------------------------------------------------------ grouped GEMM
// C[e*CAP+m][n] = sum_k A[e*CAP+m][k] * W[e][k][n]; W fp32 transposed+cvt to
// bf16 [n][k] LDS tiles in-kernel. 128x128 tile, BK=64, 4 waves (2x2),
// double-buffered LDS (64KB -> 2 blocks/CU), ONE barrier per K-tile:
//   L(t+1) fp32 loads -> frag ds_reads(t) -> ADMA A(t+1) -> lgkm0 ->
//   32 MFMA -> vmcnt(4) [L retired, ADMA in flight] -> B-writes(t+1) ->
//   vmcnt(0)+lgkm0 -> s_barrier.
// Legal with dbuf: iter t reads buf[t&1], writes buf[t^1]; all reads of
// buf[t^1] (tile t-1) completed before iter t-1's trailing barrier.
// Swizzles (both-sides, rule #21): A chunk c -> c^(row&7) (pre-swizzled
// global source, linear gload_lds dest); B chunk c -> c^S(n),
// S(n)=(n^(n>>3))&7 (uint4 reg-staged writes), matched on ds_read.
template <int K, int NN, bool SILU>
__global__ __launch_bounds__(256, 2) void k_gemm(const u16* __restrict__ A,
                                                 const float* __restrict__ Wf,
                                                 u16* __restrict__ Cout) {
  constexpr int MT = CAP / 128;        // 4
  constexpr int NT = NN / 128;
  constexpr int NWG = NEXP * MT * NT;  // %8 == 0
  constexpr int Q = NWG / 8;
  constexpr int KT = K / 64;           // 8 or 16
  int wg = (blockIdx.x % 8) * Q + blockIdx.x / 8;  // XCD chunked swizzle
  int e = wg / (MT * NT);
  int rm = wg % (MT * NT);
  int mt = rm / NT, nt = rm % NT;

  const u16* Ab = A + ((size_t)e * CAP + (size_t)mt * 128) * K;

  // LDS: A bufs at 0/16384; B bufs at 32768/49152. 64KB total.
  __shared__ __align__(16) char smc[65536];

  int t_ = threadIdx.x;
  int lane = t_ & 63, wv = t_ >> 6;
  int wm = wv >> 1, wn = wv & 1;        // 2x2 wave grid; wave out = 64x64
  int l15 = lane & 15, lhi = lane >> 4;

  // ---- A staging (global_load_lds): row t_>>3 (0..31/call), chunk t_&7
  int srow = t_ >> 3;
  int gchunk = (t_ & 7) ^ (srow & 7);
  const u16* gA = Ab + (size_t)srow * K + gchunk * 8;
#define STAGE_A(tn)                                                          \
  do {                                                                       \
    char* d_ = smc + ((tn) & 1) * 16384 + wv * 1024;                         \
    const u16* s_ = gA + (size_t)(tn) * 64;                                  \
    GLOAD_LDS16(s_, d_);                                                     \
    GLOAD_LDS16(s_ + (size_t)32 * K, d_ + 4096);                             \
    GLOAD_LDS16(s_ + (size_t)64 * K, d_ + 8192);                             \
    GLOAD_LDS16(s_ + (size_t)96 * K, d_ + 12288);                            \
  } while (0)

  // ---- B staging (reg-staged transpose+cvt from fp32 W[k][n])
  // thread unit: k0 = (t_>>5)*8 (8 rows), n0 = (t_&31)*4 (4 cols)
  int kunit = t_ >> 5;                  // 0..7
  int nunit = t_ & 31;                  // 0..31
  const float* gWb = Wf + (size_t)e * K * NN + (size_t)(kunit * 8) * NN +
                     (size_t)nt * 128 + nunit * 4;
  int wbo[4];
#pragma unroll
  for (int i = 0; i < 4; i++) {
    int n = nunit * 4 + i;
    int S = (n ^ (n >> 3)) & 7;
    wbo[i] = 32768 + n * 128 + ((kunit ^ S) << 4);
  }

  f32x4 acc[4][4];
#pragma unroll
  for (int i = 0; i < 4; i++)
#pragma unroll
    for (int j = 0; j < 4; j++) {
      f32x4 z = {0.f, 0.f, 0.f, 0.f};
      acc[i][j] = z;
    }
  bf16x8 a[4][2], b[4][2];

  // ---- fragment read offsets (bytes within a buffer)
  int aof[4][2], bof[4][2];
#pragma unroll
  for (int f = 0; f < 4; f++) {
    int ar = wm * 64 + f * 16 + l15;
    aof[f][0] = ar * 128 + ((lhi ^ (ar & 7)) << 4);
    aof[f][1] = ar * 128 + (((4 + lhi) ^ (ar & 7)) << 4);
    int br = wn * 64 + f * 16 + l15;
    int Sb = (br ^ (br >> 3)) & 7;
    bof[f][0] = br * 128 + ((lhi ^ Sb) << 4);
    bof[f][1] = br * 128 + (((4 + lhi) ^ Sb) << 4);
  }

#define LOAD_L(tn)                                                           \
  do {                                                                       \
    const float* g_ = gWb + (size_t)(tn) * 64 * NN;                          \
    L0 = *reinterpret_cast<const float4*>(g_);                               \
    L1 = *reinterpret_cast<const float4*>(g_ + (size_t)1 * NN);              \
    L2 = *reinterpret_cast<const float4*>(g_ + (size_t)2 * NN);              \
    L3 = *reinterpret_cast<const float4*>(g_ + (size_t)3 * NN);              \
    L4 = *reinterpret_cast<const float4*>(g_ + (size_t)4 * NN);              \
    L5 = *reinterpret_cast<const float4*>(g_ + (size_t)5 * NN);              \
    L6 = *reinterpret_cast<const float4*>(g_ + (size_t)6 * NN);              \
    L7 = *reinterpret_cast<const float4*>(g_ + (size_t)7 * NN);              \
  } while (0)

#define WRITE_B(bufsel)                                                      \
  do {                                                                       \
    char* w_ = smc + (bufsel) * 16384;                                       \
    _Pragma("unroll") for (int i = 0; i < 4; i++) {                          \
      uint4 v;                                                               \
      v.x = pkbf(L0[i], L1[i]); v.y = pkbf(L2[i], L3[i]);                    \
      v.z = pkbf(L4[i], L5[i]); v.w = pkbf(L6[i], L7[i]);                    \
      *reinterpret_cast<uint4*>(w_ + wbo[i]) = v;                            \
    }                                                                        \
  } while (0)

  float4 L0, L1, L2, L3, L4, L5, L6, L7;

  // ---- prologue: A(0) DMA + L(0) -> B(0) into slot 0
  STAGE_A(0);
  LOAD_L(0);
  asm volatile("s_waitcnt vmcnt(0)" ::: "memory");  // L(0) in regs, A(0) resident
  __builtin_amdgcn_sched_barrier(0);
  WRITE_B(0);
  asm volatile("s_waitcnt lgkmcnt(0)" ::: "memory");
  __builtin_amdgcn_sched_barrier(0);
  __builtin_amdgcn_s_barrier();

  for (int t = 0; t < KT; t++) {
    const char* pA = smc + (t & 1) * 16384;
    const char* pB = smc + 32768 + (t & 1) * 16384;
    int nb = (t + 1) & 1;

    if (t + 1 < KT) LOAD_L(t + 1);        // 8 VMEM (oldest in queue)
#pragma unroll
    for (int f = 0; f < 4; f++) {
      a[f][0] = *reinterpret_cast<const bf16x8*>(pA + aof[f][0]);
      a[f][1] = *reinterpret_cast<const bf16x8*>(pA + aof[f][1]);
      b[f][0] = *reinterpret_cast<const bf16x8*>(pB + bof[f][0]);
      b[f][1] = *reinterpret_cast<const bf16x8*>(pB + bof[f][1]);
    }
    if (t + 1 < KT) STAGE_A(t + 1);       // ADMA after L in vmcnt order
    asm volatile("s_waitcnt lgkmcnt(0)" ::: "memory");  // frags in regs
    __builtin_amdgcn_sched_barrier(0);

    __builtin_amdgcn_s_setprio(1);
#pragma unroll
    for (int mf = 0; mf < 4; mf++)
#pragma unroll
      for (int nf = 0; nf < 4; nf++)
#pragma unroll
        for (int kk = 0; kk < 2; kk++)
          acc[mf][nf] = __builtin_amdgcn_mfma_f32_16x16x32_bf16(a[mf][kk], b[nf][kk], acc[mf][nf], 0, 0, 0);
    __builtin_amdgcn_s_setprio(0);

    if (t + 1 < KT) {
      asm volatile("s_waitcnt vmcnt(4)" ::: "memory");  // L(t+1) retired; ADMA in flight
      __builtin_amdgcn_sched_barrier(0);
      WRITE_B(nb);
    }
    asm volatile("s_waitcnt vmcnt(0) lgkmcnt(0)" ::: "memory");  // A(t+1)+B(t+1) landed
    __builtin_amdgcn_sched_barrier(0);
    __builtin_amdgcn_s_barrier();
  }
#undef STAGE_A
#undef LOAD_L
#undef WRITE_B

  // epilogue: D row = lhi*4+reg, col = l15 (verified C/D layout); bf16 out
#pragma unroll
  for (int mf = 0; mf < 4; mf++) {
#pragma unroll
    for (int nf = 0; nf < 4; nf++) {
#pragma unroll
      for (int rg = 0; rg < 4; rg++) {
        float v = acc[mf][nf][rg];
        int grow = mt * 128 + wm * 64 + mf * 16 + lhi * 4 + rg;
        int gcol = nt * 128 + wn * 64 + nf * 16 + l15;
        size_t off = ((size_t)e * CAP + grow) * NN + gcol;
        if constexpr (SILU) v = v / (1.0f + __expf(-v));  // silu
        Cout[off] = f2bf(v);
      }
    }
  }
}

// ------------------------------------------- weighted combine (no atomics)
__global__ void k_combine(const u16* __restrict__ yws, const int* __restrict__ slot_pos,
                          const float* __restrict__ w, float* __restrict__ out) {
  int tk = blockIdx.x;
  int t = threadIdx.x;  // 256 threads, 2 elems each
  int p0 = slot_pos[2 * tk], p1 = slot_pos[2 * tk + 1];
  float w0 = w[2 * tk], w1 = w[2 * tk + 1];
  unsigned ua = reinterpret_cast<const unsigned*>(yws + (size_t)p0 * HID)[t];
  unsigned ub = reinterpret_cast<const unsigned*>(yws + (size_t)p1 * HID)[t];
  float2 o;
  o.x = w0 * bf2f(ua & 0xffffu) + w1 * bf2f(ub & 0xffffu);
  o.y = w0 * bf2f(ua >> 16) + w1 * bf2f(ub >> 16);
  reinterpret_cast<float2*>(out + (size_t)tk * HID)[t] = o;
}

// ---------------------------------------------------------------- launcher
extern "C" void kernel_launch(void* const* d_in, const int* in_sizes, int n_in,
                              void* d_out, int out_size, void* d_ws, size_t ws_size,
                              hipStream_t stream) {
  const float* hs = (const float*)d_in[0];
  const float* wts = (const float*)d_in[1];
  const int* ids = (const int*)d_in[2];
  const float* W1 = (const float*)d_in[3];
  const float* W2 = (const float*)d_in[4];
  float* out = (float*)d_out;

  char* ws = (char*)d_ws;
  size_t o = 0;
  int* cnt = (int*)(ws + o);       o += 1024;
  int* slot_pos = (int*)(ws + o);  o += (size_t)NASSIGN * 4;
  int* tok_of = (int*)(ws + o);    o += (size_t)NASSIGN * 4;
  o = (o + 255) & ~(size_t)255;
  u16* Xg = (u16*)(ws + o);        o += (size_t)NASSIGN * HID * 2;      // 32 MB
  u16* hid = (u16*)(ws + o);       o += (size_t)NASSIGN * FFN * 2;      // 64 MB
  u16* yws = (u16*)(ws + o);       o += (size_t)NASSIGN * HID * 2;      // 32 MB

  hipMemsetAsync(cnt, 0, NEXP * sizeof(int), stream);
  k_route<<<(NASSIGN + 255) / 256, 256, 0, stream>>>(ids, cnt, tok_of, slot_pos);
  k_gather<<<NASSIGN / 4, 256, 0, stream>>>(hs, tok_of, Xg);
  k_gemm<HID, FFN, true><<<NEXP * (CAP / 128) * (FFN / 128), 256, 0, stream>>>(Xg, W1, hid);
  k_gemm<FFN, HID, false><<<NEXP * (CAP / 128) * (HID / 128), 256, 0, stream>>>(hid, W2, yws);
  k_combine<<<B_TOK, 256, 0, stream>>>(yws, slot_pos, wts, out);
}